// Round 3
// baseline (87069.128 us; speedup 1.0000x reference)
//
#include <hip/hip_runtime.h>
#include <cstdint>
#include <cstddef>

// B=256 batch, n=512 classes/steps, H=512 hidden, 3H=1536.
#define BB 256
#define NN 512
#define HH 512
#define G3 1536
#define NBLK 128  // persistent grid blocks

typedef short bf16x8 __attribute__((ext_vector_type(8)));
typedef float f32x4 __attribute__((ext_vector_type(4)));

// ---------------- static device state (avoids ws_size limits) ----------------
// Weight planes: bf16 hi plane then lo plane, fragment-order layout:
//   offset(row c, k) = ((tile(c))*16 + S)*512 + qu*128 + ci*8 + j
//   where tile = c>>4 (n-tiles), ci = c&15, S = k>>5, qu = (k>>3)&3, j = k&7.
__device__ short g_Whh0[2 * 786432];
__device__ short g_Whh1[2 * 786432];
__device__ short g_Wih1[2 * 786432];
__device__ short g_Wout[2 * 262144];
// h-state planes (double buffered): hi[131072] then lo[131072] shorts.
//   offset(b,h) = (b>>4)*8192 + (h>>5)*512 + ((h>>3)&3)*128 + (b&15)*8 + (h&7)
__device__ short g_h0p[2][2 * 131072];
__device__ short g_h1p[2][2 * 131072];
__device__ float g_h0f[2][131072];  // exact fp32 h for recurrence hold-term
__device__ float g_h1f[2][131072];
__device__ float g_gh1[BB * G3];    // gate-interleaved [b][hb*48+g*16+ci]
__device__ float g_logits[BB * NN];
__device__ float g_WihT[NN * G3];   // W_ih0 transposed (one-hot gather rows)
__device__ float g_ones[G3];        // gi0 at t=0 (includes b_ih0)
__device__ float g_lp[BB];
__device__ unsigned g_avail[BB * 16];
__device__ int g_idx[BB];
__device__ unsigned g_bar[2];       // {count, generation}

// ---------------- bf16 hi/lo split helpers ----------------
__device__ __forceinline__ unsigned short bf16_rne(float f) {
  uint32_t u = __float_as_uint(f);
  uint32_t r = u + 0x7FFFu + ((u >> 16) & 1u);
  return (unsigned short)(r >> 16);
}
__device__ __forceinline__ float bf16_to_f(unsigned short h) {
  return __uint_as_float(((uint32_t)h) << 16);
}

// ---------------- threefry2x32 (JAX-exact, 20 rounds) ----------------
__device__ __forceinline__ uint32_t rotl32(uint32_t v, int r) {
  return (v << r) | (v >> (32 - r));
}
__device__ __forceinline__ void threefry2x32(uint32_t k0, uint32_t k1,
                                             uint32_t x0, uint32_t x1,
                                             uint32_t& o0, uint32_t& o1) {
  uint32_t k2 = k0 ^ k1 ^ 0x1BD11BDAu;
  x0 += k0; x1 += k1;
  x0 += x1; x1 = rotl32(x1, 13); x1 ^= x0;
  x0 += x1; x1 = rotl32(x1, 15); x1 ^= x0;
  x0 += x1; x1 = rotl32(x1, 26); x1 ^= x0;
  x0 += x1; x1 = rotl32(x1, 6);  x1 ^= x0;
  x0 += k1; x1 += k2 + 1u;
  x0 += x1; x1 = rotl32(x1, 17); x1 ^= x0;
  x0 += x1; x1 = rotl32(x1, 29); x1 ^= x0;
  x0 += x1; x1 = rotl32(x1, 16); x1 ^= x0;
  x0 += x1; x1 = rotl32(x1, 24); x1 ^= x0;
  x0 += k2; x1 += k0 + 2u;
  x0 += x1; x1 = rotl32(x1, 13); x1 ^= x0;
  x0 += x1; x1 = rotl32(x1, 15); x1 ^= x0;
  x0 += x1; x1 = rotl32(x1, 26); x1 ^= x0;
  x0 += x1; x1 = rotl32(x1, 6);  x1 ^= x0;
  x0 += k0; x1 += k1 + 3u;
  x0 += x1; x1 = rotl32(x1, 17); x1 ^= x0;
  x0 += x1; x1 = rotl32(x1, 29); x1 ^= x0;
  x0 += x1; x1 = rotl32(x1, 16); x1 ^= x0;
  x0 += x1; x1 = rotl32(x1, 24); x1 ^= x0;
  x0 += k1; x1 += k2 + 4u;
  x0 += x1; x1 = rotl32(x1, 13); x1 ^= x0;
  x0 += x1; x1 = rotl32(x1, 15); x1 ^= x0;
  x0 += x1; x1 = rotl32(x1, 26); x1 ^= x0;
  x0 += x1; x1 = rotl32(x1, 6);  x1 ^= x0;
  x0 += k2; x1 += k0 + 5u;
  o0 = x0; o1 = x1;
}

// ---------------- prelude kernels ----------------
__global__ __launch_bounds__(256) void init_state_kernel() {
  int i = blockIdx.x * 256 + threadIdx.x;  // grid 1024*256 = 262144
  if (i < 262144) {
    ((float*)g_h0f)[i] = 0.0f;
    ((float*)g_h1f)[i] = 0.0f;
    ((uint32_t*)g_h0p)[i] = 0u;  // 262144 uints = 524288 shorts (both bufs)
    ((uint32_t*)g_h1p)[i] = 0u;
  }
  if (i < BB * 16) g_avail[i] = 0xFFFFFFFFu;
  if (i < BB) { g_lp[i] = 0.0f; g_idx[i] = 0; }
  if (i == 0) { g_bar[0] = 0u; g_bar[1] = 0u; }
}

__global__ __launch_bounds__(256) void ones_row_kernel(
    const float* __restrict__ W_ih0, const float* __restrict__ b_ih0) {
  int j = blockIdx.x * 256 + threadIdx.x;
  if (j < G3) {
    const float* row = W_ih0 + (size_t)j * NN;
    float s = 0.0f;
    for (int k = 0; k < NN; ++k) s += row[k];
    g_ones[j] = s + b_ih0[j];
  }
}

__global__ __launch_bounds__(256) void transpose_kernel(
    const float* __restrict__ in) {
  __shared__ float tile[32][33];
  int bx = blockIdx.x;  // over NN, 16
  int by = blockIdx.y;  // over G3, 48
  int tx = threadIdx.x & 31;
  int ty = threadIdx.x >> 5;
  for (int i = 0; i < 32; i += 8)
    tile[ty + i][tx] = in[(size_t)(by * 32 + ty + i) * NN + bx * 32 + tx];
  __syncthreads();
  for (int i = 0; i < 32; i += 8)
    g_WihT[(size_t)(bx * 32 + ty + i) * G3 + by * 32 + tx] = tile[tx][ty + i];
}

// Split fp32 weight rows into hi/lo bf16 planes, fragment-order layout.
// rows = number of W rows (1536 or 512); plane = shorts per plane.
__global__ __launch_bounds__(256) void split_kernel(
    const float* __restrict__ W, short* __restrict__ dst, int rows,
    int plane) {
  int i = blockIdx.x * 256 + threadIdx.x;  // rows*64 threads
  if (i >= rows * 64) return;
  int c = i >> 6;       // W row
  int jb = i & 63;      // 8-elem k-chunk
  int tile = c >> 4, ci = c & 15;
  int S = jb >> 2, qu = jb & 3;
  int off = (tile * 16 + S) * 512 + qu * 128 + ci * 8;
  const float* src = W + (size_t)c * 512 + jb * 8;
  float v[8];
  *(float4*)v = *(const float4*)src;
  *(float4*)(v + 4) = *(const float4*)(src + 4);
  short hb[8], lb[8];
#pragma unroll
  for (int e = 0; e < 8; ++e) {
    unsigned short h = bf16_rne(v[e]);
    hb[e] = (short)h;
    lb[e] = (short)bf16_rne(v[e] - bf16_to_f(h));
  }
  *(bf16x8*)(dst + off) = *(const bf16x8*)hb;
  *(bf16x8*)(dst + plane + off) = *(const bf16x8*)lb;
}

// ---------------- grid barrier (generation-based, device scope) ----------------
__device__ __forceinline__ void grid_barrier() {
  __syncthreads();
  if (threadIdx.x == 0) {
    __threadfence();  // release my block's writes
    unsigned g = atomicAdd(&g_bar[1], 0u);  // read generation
    __threadfence();  // order gen-read before arrive
    unsigned a = atomicAdd(&g_bar[0], 1u);
    if (a == NBLK - 1) {
      atomicExch(&g_bar[0], 0u);
      atomicAdd(&g_bar[1], 1u);
    } else {
      while (atomicAdd(&g_bar[1], 0u) == g) __builtin_amdgcn_s_sleep(2);
    }
    __threadfence();  // acquire: invalidate stale cache
  }
  __syncthreads();
}

// ---------------- fragment-GEMM inner loop (no LDS, no conversion) ----------
// acc[mg][j] over 2 m-groups x NT consecutive n-tiles (tile base tb).
template <int NT>
__device__ __forceinline__ void mfma_tiles(const short* __restrict__ Ap,
                                           const short* __restrict__ Wp,
                                           int wplane, int mc0, int tb,
                                           int lnoff, f32x4 acc[2][NT]) {
#pragma unroll
  for (int S = 0; S < 16; ++S) {
    bf16x8 ah[2], al[2];
#pragma unroll
    for (int mg = 0; mg < 2; ++mg) {
      int off = (mc0 + mg) * 8192 + S * 512 + lnoff;
      ah[mg] = *(const bf16x8*)(Ap + off);
      al[mg] = *(const bf16x8*)(Ap + 131072 + off);
    }
#pragma unroll
    for (int j = 0; j < NT; ++j) {
      int woff = ((tb + j) * 16 + S) * 512 + lnoff;
      bf16x8 bh = *(const bf16x8*)(Wp + woff);
      bf16x8 bl = *(const bf16x8*)(Wp + wplane + woff);
#pragma unroll
      for (int mg = 0; mg < 2; ++mg) {
        acc[mg][j] = __builtin_amdgcn_mfma_f32_16x16x32_bf16(ah[mg], bh,
                                                             acc[mg][j], 0, 0, 0);
        acc[mg][j] = __builtin_amdgcn_mfma_f32_16x16x32_bf16(ah[mg], bl,
                                                             acc[mg][j], 0, 0, 0);
        acc[mg][j] = __builtin_amdgcn_mfma_f32_16x16x32_bf16(al[mg], bh,
                                                             acc[mg][j], 0, 0, 0);
      }
    }
  }
}

__device__ __forceinline__ void store_h_split(short* plane, int b, int h,
                                              float v) {
  int off = (b >> 4) * 8192 + (h >> 5) * 512 + ((h >> 3) & 3) * 128 +
            (b & 15) * 8 + (h & 7);
  unsigned short hi = bf16_rne(v);
  plane[off] = (short)hi;
  plane[131072 + off] = (short)bf16_rne(v - bf16_to_f(hi));
}

// ---------------- persistent kernel: all 512 steps ----------------
__global__ __launch_bounds__(256) void persist_kernel(
    const float* __restrict__ b_ih0, const float* __restrict__ b_hh0,
    const float* __restrict__ b_ih1, const float* __restrict__ b_hh1,
    const float* __restrict__ b_out, float* __restrict__ out_perm,
    float* __restrict__ out_lp) {
  const int bid = blockIdx.x;
  const int tid = threadIdx.x;
  const int w = tid >> 6, ln = tid & 63;
  const int ci = ln & 15, qu = ln >> 4;
  const int lnoff = ln * 8;

  __shared__ float rv[2][256];
  __shared__ int ri[2][256];
  __shared__ float rm[2][256];

  for (int t = 0; t < NN; ++t) {
    const int rb = t & 1, wb = rb ^ 1;

    // ---------- phase A: gh0+cell0 -> h0(wb)  ||  gh1 ----------
    {
      const int mode = bid >> 6;           // 0: layer0, 1: gh1
      const int mt = (bid >> 5) & 1;       // 128-row half
      const int hb = bid & 31;             // h-block
      const short* Ap = mode ? g_h1p[rb] : g_h0p[rb];
      const short* Wp = mode ? g_Whh1 : g_Whh0;
      const int mc0 = mt * 8 + w * 2;      // A chunk base (m>>4)
      f32x4 acc[2][3];
#pragma unroll
      for (int mg = 0; mg < 2; ++mg)
#pragma unroll
        for (int g = 0; g < 3; ++g) acc[mg][g] = (f32x4){0.f, 0.f, 0.f, 0.f};
      mfma_tiles<3>(Ap, Wp, 786432, mc0, hb * 3, lnoff, acc);

      const int h = hb * 16 + ci;
      if (mode == 0) {
        float br = b_hh0[h], bz = b_hh0[HH + h], bn = b_hh0[2 * HH + h];
        float bi0 = b_ih0[h], bi1 = b_ih0[HH + h], bi2 = b_ih0[2 * HH + h];
#pragma unroll
      for (int mg = 0; mg < 2; ++mg)
#pragma unroll
        for (int r = 0; r < 4; ++r) {
          int b = mt * 128 + w * 32 + mg * 16 + qu * 4 + r;
          float ir, iz, in_;
          if (t == 0) {
            ir = g_ones[h]; iz = g_ones[HH + h]; in_ = g_ones[2 * HH + h];
          } else {
            const float* wr_ = g_WihT + (size_t)g_idx[b] * G3;
            ir = wr_[h] + bi0;
            iz = wr_[HH + h] + bi1;
            in_ = wr_[2 * HH + h] + bi2;
          }
          float gr = acc[mg][0][r] + br, gz = acc[mg][1][r] + bz,
                gn = acc[mg][2][r] + bn;
          float rr = 1.f / (1.f + expf(-(ir + gr)));
          float zz = 1.f / (1.f + expf(-(iz + gz)));
          float ng = tanhf(in_ + rr * gn);
          float hold = g_h0f[rb][(size_t)b * HH + h];
          float hn = (1.f - zz) * ng + zz * hold;
          g_h0f[wb][(size_t)b * HH + h] = hn;
          store_h_split(g_h0p[wb], b, h, hn);
        }
      } else {
        float b0_ = b_hh1[h], b1_ = b_hh1[HH + h], b2_ = b_hh1[2 * HH + h];
#pragma unroll
        for (int mg = 0; mg < 2; ++mg)
#pragma unroll
          for (int r = 0; r < 4; ++r) {
            int b = mt * 128 + w * 32 + mg * 16 + qu * 4 + r;
            float* dst = g_gh1 + (size_t)b * G3 + hb * 48 + ci;
            dst[0] = acc[mg][0][r] + b0_;
            dst[16] = acc[mg][1][r] + b1_;
            dst[32] = acc[mg][2][r] + b2_;
          }
      }
    }
    grid_barrier();

    // ---------- phase B: gi1+cell1 -> h1(wb) ----------
    if (bid < 64) {
      const int mt = bid >> 5, hb = bid & 31;
      const int mc0 = mt * 8 + w * 2;
      f32x4 acc[2][3];
#pragma unroll
      for (int mg = 0; mg < 2; ++mg)
#pragma unroll
        for (int g = 0; g < 3; ++g) acc[mg][g] = (f32x4){0.f, 0.f, 0.f, 0.f};
      mfma_tiles<3>(g_h0p[wb], g_Wih1, 786432, mc0, hb * 3, lnoff, acc);

      const int h = hb * 16 + ci;
      float bi0 = b_ih1[h], bi1 = b_ih1[HH + h], bi2 = b_ih1[2 * HH + h];
#pragma unroll
      for (int mg = 0; mg < 2; ++mg)
#pragma unroll
        for (int r = 0; r < 4; ++r) {
          int b = mt * 128 + w * 32 + mg * 16 + qu * 4 + r;
          const float* gsrc = g_gh1 + (size_t)b * G3 + hb * 48 + ci;
          float rr = 1.f / (1.f + expf(-(acc[mg][0][r] + bi0 + gsrc[0])));
          float zz = 1.f / (1.f + expf(-(acc[mg][1][r] + bi1 + gsrc[16])));
          float ng = tanhf(acc[mg][2][r] + bi2 + rr * gsrc[32]);
          float hold = g_h1f[rb][(size_t)b * HH + h];
          float hn = (1.f - zz) * ng + zz * hold;
          g_h1f[wb][(size_t)b * HH + h] = hn;
          store_h_split(g_h1p[wb], b, h, hn);
        }
    }
    grid_barrier();

    // ---------- phase C: logits = h1(wb) @ W_out^T + b_out ----------
    if (bid < 32) {
      const int mt = bid >> 4, q = bid & 15;
      const int mc0 = mt * 8 + w * 2;
      f32x4 acc[2][2];
#pragma unroll
      for (int mg = 0; mg < 2; ++mg)
#pragma unroll
        for (int j = 0; j < 2; ++j) acc[mg][j] = (f32x4){0.f, 0.f, 0.f, 0.f};
      mfma_tiles<2>(g_h1p[wb], g_Wout, 262144, mc0, q * 2, lnoff, acc);
#pragma unroll
      for (int j = 0; j < 2; ++j) {
        int n = (q * 2 + j) * 16 + ci;
        float bo = b_out[n];
#pragma unroll
        for (int mg = 0; mg < 2; ++mg)
#pragma unroll
          for (int r = 0; r < 4; ++r) {
            int b = mt * 128 + w * 32 + mg * 16 + qu * 4 + r;
            g_logits[(size_t)b * NN + n] = acc[mg][j][r] + bo;
          }
      }
    }
    grid_barrier();

    // ---------- phase D: sampler (rows bid and bid+128) ----------
    {
      const int b0 = bid;
      uint32_t tp = (uint32_t)(t & 255);
      uint32_t a0, a1, c0, c1;
      threefry2x32(0u, 42u, 2u * tp, 2u * tp + 512u, a0, a1);
      threefry2x32(0u, 42u, 2u * tp + 1u, 2u * tp + 1u + 512u, c0, c1);
      uint32_t sk0 = (t < 256) ? a0 : a1;
      uint32_t sk1 = (t < 256) ? c0 : c1;

      float bestv[2] = {-1.0f / 0.0f, -1.0f / 0.0f};
      int besti[2] = {0, 0};
      float mymax[2] = {-1.0f / 0.0f, -1.0f / 0.0f};
      float ml[2][2];

#pragma unroll
      for (int j = 0; j < 2; ++j) {
        int c = tid + j * 256;
        uint32_t cnt = (uint32_t)b0 * 512u + (uint32_t)c;
        uint32_t r0, r1;
        threefry2x32(sk0, sk1, cnt, cnt + 65536u, r0, r1);
#pragma unroll
        for (int rw = 0; rw < 2; ++rw) {
          int b = b0 + rw * 128;
          uint32_t bits = rw ? r1 : r0;
          float u = __uint_as_float((bits >> 9) | 0x3f800000u) - 1.0f;
          if (u == 0.0f) u = 1.17549435e-38f;
          float g = -logf(-logf(u));
          float l = g_logits[(size_t)b * NN + c];
          bool av = (g_avail[b * 16 + (c >> 5)] >> (c & 31)) & 1u;
          float mlv = av ? l : -1.0e9f;
          ml[rw][j] = mlv;
          float v = g + mlv;
          if (v > bestv[rw] || (v == bestv[rw] && c < besti[rw])) {
            bestv[rw] = v; besti[rw] = c;
          }
          mymax[rw] = fmaxf(mymax[rw], mlv);
        }
      }
      rv[0][tid] = bestv[0]; ri[0][tid] = besti[0]; rm[0][tid] = mymax[0];
      rv[1][tid] = bestv[1]; ri[1][tid] = besti[1]; rm[1][tid] = mymax[1];
      __syncthreads();
      for (int s = 128; s > 0; s >>= 1) {
        if (tid < s) {
#pragma unroll
          for (int rw = 0; rw < 2; ++rw) {
            float v2 = rv[rw][tid + s]; int i2 = ri[rw][tid + s];
            if (v2 > rv[rw][tid] || (v2 == rv[rw][tid] && i2 < ri[rw][tid])) {
              rv[rw][tid] = v2; ri[rw][tid] = i2;
            }
            rm[rw][tid] = fmaxf(rm[rw][tid], rm[rw][tid + s]);
          }
        }
        __syncthreads();
      }
      float m0 = rm[0][0], m1 = rm[1][0];
      int sel0 = ri[0][0], sel1 = ri[1][0];
      __syncthreads();
      rm[0][tid] = expf(ml[0][0] - m0) + expf(ml[0][1] - m0);
      rm[1][tid] = expf(ml[1][0] - m1) + expf(ml[1][1] - m1);
      __syncthreads();
      for (int s = 128; s > 0; s >>= 1) {
        if (tid < s) {
          rm[0][tid] += rm[0][tid + s];
          rm[1][tid] += rm[1][tid + s];
        }
        __syncthreads();
      }
      if (tid < 2) {
        int rw = tid;
        int b = b0 + rw * 128;
        float m = rw ? m1 : m0;
        int sel = rw ? sel1 : sel0;
        float ssum = rm[rw][0];
        float lsel = g_logits[(size_t)b * NN + sel];
        float p = expf(lsel - m) / ssum;
        float lpn = g_lp[b] + logf(p + 1e-9f);
        g_lp[b] = lpn;
        out_lp[b] = lpn;
        g_idx[b] = sel;
        g_avail[b * 16 + (sel >> 5)] &= ~(1u << (sel & 31));
        out_perm[(size_t)b * NN * NN + (size_t)t * NN + sel] = 1.0f;
      }
    }
    grid_barrier();
  }
}

// ---------------- host ----------------
extern "C" void kernel_launch(void* const* d_in, const int* in_sizes, int n_in,
                              void* d_out, int out_size, void* d_ws,
                              size_t ws_size, hipStream_t stream) {
  (void)in_sizes; (void)n_in; (void)d_ws; (void)ws_size;
  const float* W_ih0 = (const float*)d_in[1];
  const float* W_hh0 = (const float*)d_in[2];
  const float* b_ih0 = (const float*)d_in[3];
  const float* b_hh0 = (const float*)d_in[4];
  const float* W_ih1 = (const float*)d_in[5];
  const float* W_hh1 = (const float*)d_in[6];
  const float* b_ih1 = (const float*)d_in[7];
  const float* b_hh1 = (const float*)d_in[8];
  const float* W_out = (const float*)d_in[9];
  const float* b_out = (const float*)d_in[10];

  float* out = (float*)d_out;
  float* out_lp = out + (size_t)BB * NN * NN;

  hipMemsetAsync(d_out, 0, (size_t)out_size * sizeof(float), stream);
  init_state_kernel<<<1024, 256, 0, stream>>>();
  ones_row_kernel<<<6, 256, 0, stream>>>(W_ih0, b_ih0);
  transpose_kernel<<<dim3(16, 48), 256, 0, stream>>>(W_ih0);

  short* whh0;  hipGetSymbolAddress((void**)&whh0, HIP_SYMBOL(g_Whh0));
  short* whh1;  hipGetSymbolAddress((void**)&whh1, HIP_SYMBOL(g_Whh1));
  short* wih1;  hipGetSymbolAddress((void**)&wih1, HIP_SYMBOL(g_Wih1));
  short* wout;  hipGetSymbolAddress((void**)&wout, HIP_SYMBOL(g_Wout));
  split_kernel<<<384, 256, 0, stream>>>(W_hh0, whh0, G3, 786432);
  split_kernel<<<384, 256, 0, stream>>>(W_hh1, whh1, G3, 786432);
  split_kernel<<<384, 256, 0, stream>>>(W_ih1, wih1, G3, 786432);
  split_kernel<<<128, 256, 0, stream>>>(W_out, wout, NN, 262144);

  persist_kernel<<<NBLK, 256, 0, stream>>>(b_ih0, b_hh0, b_ih1, b_hh1, b_out,
                                           out, out_lp);
}

// Round 4
// 43858.850 us; speedup vs baseline: 1.9852x; 1.9852x over previous
//
#include <hip/hip_runtime.h>
#include <cstdint>
#include <cstddef>

// B=256 batch, n=512 classes/steps, H=512 hidden, 3H=1536.
#define BB 256
#define NN 512
#define HH 512
#define G3 1536
#define NBLK 256  // persistent grid: one block per CU

typedef short bf16x8 __attribute__((ext_vector_type(8)));
typedef float f32x4 __attribute__((ext_vector_type(4)));

// ---------------- static device state ----------------
// Weight planes (hi then lo), fragment order. For 1536-row weights the tile
// index is GATE-INTERLEAVED: tile(c) = ((c&511)>>4)*3 + (c>>9), so tiles
// {hb*3+g} hold rows {g*512 + hb*16 + i} — epilogue gate g <-> acc[g].
// For W_out (512 rows): tile = c>>4.
__device__ __align__(16) short g_Whh0[2 * 786432];
__device__ __align__(16) short g_Whh1[2 * 786432];
__device__ __align__(16) short g_Wih1[2 * 786432];
__device__ __align__(16) short g_Wout[2 * 262144];
// h-state planes, double buffered; hi[131072] then lo[131072] shorts.
// off(b,h) = (b>>4)*8192 + (h>>5)*512 + ((h>>3)&3)*128 + (b&15)*8 + (h&7)
__device__ __align__(16) short g_h0p[2][2 * 131072];
__device__ __align__(16) short g_h1p[2][2 * 131072];
__device__ __align__(16) float g_gh1[BB * G3];     // [b][g*512+h]
__device__ __align__(16) float g_logits[BB * NN];
__device__ __align__(16) float g_WihT[NN * G3];    // W_ih0^T rows (cached)
__device__ __align__(16) float g_ones[G3];         // gi0 at t=0 (incl b_ih0)
__device__ int g_idx[BB];
__device__ unsigned g_bcnt[256];  // 8 groups, stride 32 (128B apart)
__device__ unsigned g_bmaster;
__device__ unsigned g_bgen;

// ---------------- coherent (agent-scope, no-invalidate) access ----------------
__device__ __forceinline__ unsigned long long cload_u64(const void* p) {
  return __hip_atomic_load((unsigned long long*)p, __ATOMIC_RELAXED,
                           __HIP_MEMORY_SCOPE_AGENT);
}
__device__ __forceinline__ bf16x8 cload_frag(const short* p) {
  union { unsigned long long q[2]; bf16x8 v; } u;
  u.q[0] = cload_u64(p);
  u.q[1] = cload_u64(p + 4);
  return u.v;
}
__device__ __forceinline__ float cloadf(const float* p) {
  return __hip_atomic_load((float*)p, __ATOMIC_RELAXED,
                           __HIP_MEMORY_SCOPE_AGENT);
}
__device__ __forceinline__ void cstoref(float* p, float v) {
  __hip_atomic_store(p, v, __ATOMIC_RELAXED, __HIP_MEMORY_SCOPE_AGENT);
}
__device__ __forceinline__ void cstores(short* p, short v) {
  __hip_atomic_store((unsigned short*)p, (unsigned short)v, __ATOMIC_RELAXED,
                     __HIP_MEMORY_SCOPE_AGENT);
}

// ---------------- bf16 hi/lo split helpers ----------------
__device__ __forceinline__ unsigned short bf16_rne(float f) {
  uint32_t u = __float_as_uint(f);
  uint32_t r = u + 0x7FFFu + ((u >> 16) & 1u);
  return (unsigned short)(r >> 16);
}
__device__ __forceinline__ float bf16_to_f(unsigned short h) {
  return __uint_as_float(((uint32_t)h) << 16);
}

__device__ __forceinline__ void store_h_plane(short* plane, int b, int h,
                                              float v) {
  int off = (b >> 4) * 8192 + (h >> 5) * 512 + ((h >> 3) & 3) * 128 +
            (b & 15) * 8 + (h & 7);
  unsigned short hi = bf16_rne(v);
  unsigned short lo = bf16_rne(v - bf16_to_f(hi));
  cstores(plane + off, (short)hi);
  cstores(plane + 131072 + off, (short)lo);
}

// ---------------- threefry2x32 (JAX-exact, 20 rounds) ----------------
__device__ __forceinline__ uint32_t rotl32(uint32_t v, int r) {
  return (v << r) | (v >> (32 - r));
}
__device__ __forceinline__ void threefry2x32(uint32_t k0, uint32_t k1,
                                             uint32_t x0, uint32_t x1,
                                             uint32_t& o0, uint32_t& o1) {
  uint32_t k2 = k0 ^ k1 ^ 0x1BD11BDAu;
  x0 += k0; x1 += k1;
  x0 += x1; x1 = rotl32(x1, 13); x1 ^= x0;
  x0 += x1; x1 = rotl32(x1, 15); x1 ^= x0;
  x0 += x1; x1 = rotl32(x1, 26); x1 ^= x0;
  x0 += x1; x1 = rotl32(x1, 6);  x1 ^= x0;
  x0 += k1; x1 += k2 + 1u;
  x0 += x1; x1 = rotl32(x1, 17); x1 ^= x0;
  x0 += x1; x1 = rotl32(x1, 29); x1 ^= x0;
  x0 += x1; x1 = rotl32(x1, 16); x1 ^= x0;
  x0 += x1; x1 = rotl32(x1, 24); x1 ^= x0;
  x0 += k2; x1 += k0 + 2u;
  x0 += x1; x1 = rotl32(x1, 13); x1 ^= x0;
  x0 += x1; x1 = rotl32(x1, 15); x1 ^= x0;
  x0 += x1; x1 = rotl32(x1, 26); x1 ^= x0;
  x0 += x1; x1 = rotl32(x1, 6);  x1 ^= x0;
  x0 += k0; x1 += k1 + 3u;
  x0 += x1; x1 = rotl32(x1, 17); x1 ^= x0;
  x0 += x1; x1 = rotl32(x1, 29); x1 ^= x0;
  x0 += x1; x1 = rotl32(x1, 16); x1 ^= x0;
  x0 += x1; x1 = rotl32(x1, 24); x1 ^= x0;
  x0 += k1; x1 += k2 + 4u;
  x0 += x1; x1 = rotl32(x1, 13); x1 ^= x0;
  x0 += x1; x1 = rotl32(x1, 15); x1 ^= x0;
  x0 += x1; x1 = rotl32(x1, 26); x1 ^= x0;
  x0 += x1; x1 = rotl32(x1, 6);  x1 ^= x0;
  x0 += k2; x1 += k0 + 5u;
  o0 = x0; o1 = x1;
}

// ---------------- prelude kernels ----------------
__global__ __launch_bounds__(256) void init_state_kernel() {
  int i = blockIdx.x * 256 + threadIdx.x;  // grid 1024*256 = 262144
  if (i < 262144) {
    ((uint32_t*)g_h0p)[i] = 0u;  // zero both parities (524288 shorts)
    ((uint32_t*)g_h1p)[i] = 0u;
  }
  if (i < 256) g_bcnt[i] = 0u;
  if (i < BB) g_idx[i] = 0;
  if (i == 0) { g_bmaster = 0u; g_bgen = 0u; }
}

__global__ __launch_bounds__(256) void ones_row_kernel(
    const float* __restrict__ W_ih0, const float* __restrict__ b_ih0) {
  int j = blockIdx.x * 256 + threadIdx.x;
  if (j < G3) {
    const float* row = W_ih0 + (size_t)j * NN;
    float s = 0.0f;
    for (int k = 0; k < NN; ++k) s += row[k];
    g_ones[j] = s + b_ih0[j];
  }
}

__global__ __launch_bounds__(256) void transpose_kernel(
    const float* __restrict__ in) {
  __shared__ float tile[32][33];
  int bx = blockIdx.x;  // over NN, 16
  int by = blockIdx.y;  // over G3, 48
  int tx = threadIdx.x & 31;
  int ty = threadIdx.x >> 5;
  for (int i = 0; i < 32; i += 8)
    tile[ty + i][tx] = in[(size_t)(by * 32 + ty + i) * NN + bx * 32 + tx];
  __syncthreads();
  for (int i = 0; i < 32; i += 8)
    g_WihT[(size_t)(bx * 32 + ty + i) * G3 + by * 32 + tx] = tile[tx][ty + i];
}

// Split fp32 weight rows into hi/lo bf16 planes, fragment order with
// gate-interleaved tiles for 1536-row weights (see layout comment above).
__global__ __launch_bounds__(256) void split_kernel(
    const float* __restrict__ W, short* __restrict__ dst, int rows,
    int plane) {
  int i = blockIdx.x * 256 + threadIdx.x;  // rows*64 threads
  if (i >= rows * 64) return;
  int c = i >> 6;   // original W row
  int jb = i & 63;  // 8-elem k-chunk
  int ci = c & 15;
  int tile = (rows == G3) ? (((c & 511) >> 4) * 3 + (c >> 9)) : (c >> 4);
  int S = jb >> 2, qu = jb & 3;
  int off = (tile * 16 + S) * 512 + qu * 128 + ci * 8;
  const float* src = W + (size_t)c * 512 + jb * 8;
  float v[8];
  *(float4*)v = *(const float4*)src;
  *(float4*)(v + 4) = *(const float4*)(src + 4);
  short hb[8], lb[8];
#pragma unroll
  for (int e = 0; e < 8; ++e) {
    unsigned short h = bf16_rne(v[e]);
    hb[e] = (short)h;
    lb[e] = (short)bf16_rne(v[e] - bf16_to_f(h));
  }
  *(bf16x8*)(dst + off) = *(const bf16x8*)hb;
  *(bf16x8*)(dst + plane + off) = *(const bf16x8*)lb;
}

// ---------------- grid barrier: monotonic counters, no cache invalidate ----
__device__ __forceinline__ void gbar(unsigned bi) {
  __syncthreads();
  if (threadIdx.x == 0) {
    unsigned old = __hip_atomic_fetch_add(&g_bcnt[(blockIdx.x & 7) * 32], 1u,
                                          __ATOMIC_RELEASE,
                                          __HIP_MEMORY_SCOPE_AGENT);
    if (old == bi * 32u + 31u) {  // last of my 32-block group
      unsigned m = __hip_atomic_fetch_add(&g_bmaster, 1u, __ATOMIC_RELEASE,
                                          __HIP_MEMORY_SCOPE_AGENT);
      if (m == bi * 8u + 7u)  // last group
        __hip_atomic_fetch_add(&g_bgen, 1u, __ATOMIC_RELEASE,
                               __HIP_MEMORY_SCOPE_AGENT);
    }
    while (__hip_atomic_load(&g_bgen, __ATOMIC_RELAXED,
                             __HIP_MEMORY_SCOPE_AGENT) <= bi)
      __builtin_amdgcn_s_sleep(4);
  }
  __syncthreads();
}

// ---------------- fragment GEMM inner loop ----------------
__device__ __forceinline__ f32x4 mfma16(bf16x8 a, bf16x8 b, f32x4 c) {
  return __builtin_amdgcn_mfma_f32_16x16x32_bf16(a, b, c, 0, 0, 0);
}

// A (h-state planes): coherent loads. W: plain cached loads (L2-warm).
template <int NT>
__device__ __forceinline__ void gemm_frag(const short* __restrict__ Ap,
                                          const short* __restrict__ Wp,
                                          int wplane, int mc, int tb,
                                          int lnoff, f32x4* acc) {
#pragma unroll
  for (int S = 0; S < 16; ++S) {
    const int aoff = mc * 8192 + S * 512 + lnoff;
    bf16x8 ah = cload_frag(Ap + aoff);
    bf16x8 al = cload_frag(Ap + 131072 + aoff);
#pragma unroll
    for (int j = 0; j < NT; ++j) {
      const int woff = ((tb + j) * 16 + S) * 512 + lnoff;
      bf16x8 bh = *(const bf16x8*)(Wp + woff);
      bf16x8 bl = *(const bf16x8*)(Wp + wplane + woff);
      acc[j] = mfma16(ah, bh, acc[j]);
      acc[j] = mfma16(ah, bl, acc[j]);
      acc[j] = mfma16(al, bh, acc[j]);
    }
  }
}

__device__ __forceinline__ float sigf(float x) {
  return 1.0f / (1.0f + expf(-x));
}

// ---------------- persistent kernel: all 512 steps ----------------
__global__ __launch_bounds__(256) void persist_kernel(
    const float* __restrict__ b_ih0, const float* __restrict__ b_hh0,
    const float* __restrict__ b_ih1, const float* __restrict__ b_hh1,
    const float* __restrict__ b_out, float* __restrict__ out_perm,
    float* __restrict__ out_lp) {
  const int bid = blockIdx.x;
  const int tid = threadIdx.x;
  const int w = tid >> 6, ln = tid & 63;
  const int ci = ln & 15, qu = ln >> 4;
  const int lnoff = ln * 8;

  __shared__ float rv[256];
  __shared__ int ri[256];
  __shared__ float rm[256];
  __shared__ unsigned savail[16];

  // register-resident recurrence hold-terms (stable block<->tile mapping)
  float h0prev[4] = {0.f, 0.f, 0.f, 0.f};
  float h1prev[4] = {0.f, 0.f, 0.f, 0.f};
  float lp = 0.f;  // only tid 0's copy is meaningful

  if (tid < 16) savail[tid] = 0xFFFFFFFFu;
  __syncthreads();

  for (int t = 0; t < NN; ++t) {
    const int rb = t & 1, wb = rb ^ 1;

    // ---------- phase A: layer0 (bid<128) || gh1 (bid>=128) ----------
    {
      const int sub = bid & 127;
      const int mt = sub >> 5, hb = sub & 31;
      const int mc = mt * 4 + w;
      const int h = hb * 16 + ci;
      f32x4 acc[3] = {};
      if (bid < 128) {
        gemm_frag<3>(g_h0p[rb], g_Whh0, 786432, mc, hb * 3, lnoff, acc);
        const float br = b_hh0[h], bz = b_hh0[HH + h], bn = b_hh0[2 * HH + h];
        const float bi0 = b_ih0[h], bi1 = b_ih0[HH + h],
                    bi2 = b_ih0[2 * HH + h];
#pragma unroll
        for (int r = 0; r < 4; ++r) {
          const int b = mc * 16 + qu * 4 + r;
          float ir, iz, in_;
          if (t == 0) {
            ir = g_ones[h]; iz = g_ones[HH + h]; in_ = g_ones[2 * HH + h];
          } else {
            int iv = __hip_atomic_load(&g_idx[b], __ATOMIC_RELAXED,
                                       __HIP_MEMORY_SCOPE_AGENT);
            const float* wr_ = g_WihT + (size_t)iv * G3;
            ir = wr_[h] + bi0;
            iz = wr_[HH + h] + bi1;
            in_ = wr_[2 * HH + h] + bi2;
          }
          float rr = sigf(ir + acc[0][r] + br);
          float zz = sigf(iz + acc[1][r] + bz);
          float ng = tanhf(in_ + rr * (acc[2][r] + bn));
          float hn = (1.f - zz) * ng + zz * h0prev[r];
          h0prev[r] = hn;
          store_h_plane(g_h0p[wb], b, h, hn);
        }
      } else {
        gemm_frag<3>(g_h1p[rb], g_Whh1, 786432, mc, hb * 3, lnoff, acc);
        const float c0 = b_hh1[h], c1 = b_hh1[HH + h], c2 = b_hh1[2 * HH + h];
#pragma unroll
        for (int r = 0; r < 4; ++r) {
          const int b = mc * 16 + qu * 4 + r;
          float* base = g_gh1 + (size_t)b * G3;
          cstoref(base + h, acc[0][r] + c0);
          cstoref(base + 512 + h, acc[1][r] + c1);
          cstoref(base + 1024 + h, acc[2][r] + c2);
        }
      }
    }
    gbar(4u * t + 0u);

    // ---------- phase B: gi1 + cell1 -> h1(wb) (bid<128) ----------
    if (bid < 128) {
      const int mt = bid >> 5, hb = bid & 31;
      const int mc = mt * 4 + w;
      const int h = hb * 16 + ci;
      f32x4 acc[3] = {};
      gemm_frag<3>(g_h0p[wb], g_Wih1, 786432, mc, hb * 3, lnoff, acc);
      const float bi0 = b_ih1[h], bi1 = b_ih1[HH + h], bi2 = b_ih1[2 * HH + h];
#pragma unroll
      for (int r = 0; r < 4; ++r) {
        const int b = mc * 16 + qu * 4 + r;
        const float* base = g_gh1 + (size_t)b * G3;
        float gr = cloadf(base + h);
        float gz = cloadf(base + 512 + h);
        float gn = cloadf(base + 1024 + h);
        float rr = sigf(acc[0][r] + bi0 + gr);
        float zz = sigf(acc[1][r] + bi1 + gz);
        float ng = tanhf(acc[2][r] + bi2 + rr * gn);
        float hn = (1.f - zz) * ng + zz * h1prev[r];
        h1prev[r] = hn;
        store_h_plane(g_h1p[wb], b, h, hn);
      }
    }
    gbar(4u * t + 1u);

    // ---------- phase C: logits = h1(wb) @ W_out^T + b_out (bid<128) -------
    if (bid < 128) {
      const int mtp = bid >> 5, ntile = bid & 31;
      const int mc = mtp * 4 + w;
      f32x4 acc1[1] = {};
      gemm_frag<1>(g_h1p[wb], g_Wout, 262144, mc, ntile, lnoff, acc1);
      const int n = ntile * 16 + ci;
      const float bo = b_out[n];
#pragma unroll
      for (int r = 0; r < 4; ++r) {
        const int b = mc * 16 + qu * 4 + r;
        cstoref(g_logits + (size_t)b * NN + n, acc1[0][r] + bo);
      }
    }
    gbar(4u * t + 2u);

    // ---------- phase D: sampler, one row per block ----------
    {
      const int b = bid;
      uint32_t tp = (uint32_t)(t & 255);
      uint32_t a0, a1, c0, c1;
      threefry2x32(0u, 42u, 2u * tp, 2u * tp + 512u, a0, a1);
      threefry2x32(0u, 42u, 2u * tp + 1u, 2u * tp + 1u + 512u, c0, c1);
      uint32_t sk0 = (t < 256) ? a0 : a1;
      uint32_t sk1 = (t < 256) ? c0 : c1;

      float bestv = -1.0f / 0.0f;
      int besti = 0;
      float mymax = -1.0f / 0.0f;
      float ml[2];
#pragma unroll
      for (int j = 0; j < 2; ++j) {
        int c = tid + j * 256;
        uint32_t cnt = (uint32_t)(b & 127) * 512u + (uint32_t)c;
        uint32_t r0, r1;
        threefry2x32(sk0, sk1, cnt, cnt + 65536u, r0, r1);
        uint32_t bits = (b < 128) ? r0 : r1;
        float u = __uint_as_float((bits >> 9) | 0x3f800000u) - 1.0f;
        if (u == 0.0f) u = 1.17549435e-38f;
        float g = -logf(-logf(u));
        float l = cloadf(g_logits + (size_t)b * NN + c);
        bool av = (savail[c >> 5] >> (c & 31)) & 1u;
        float mlv = av ? l : -1.0e9f;
        ml[j] = mlv;
        float v = g + mlv;
        if (v > bestv || (v == bestv && c < besti)) { bestv = v; besti = c; }
        mymax = fmaxf(mymax, mlv);
      }
      rv[tid] = bestv; ri[tid] = besti; rm[tid] = mymax;
      __syncthreads();
      for (int s = 128; s > 0; s >>= 1) {
        if (tid < s) {
          float v2 = rv[tid + s]; int i2 = ri[tid + s];
          if (v2 > rv[tid] || (v2 == rv[tid] && i2 < ri[tid])) {
            rv[tid] = v2; ri[tid] = i2;
          }
          rm[tid] = fmaxf(rm[tid], rm[tid + s]);
        }
        __syncthreads();
      }
      float m = rm[0];
      int sel = ri[0];
      __syncthreads();
      rm[tid] = expf(ml[0] - m) + expf(ml[1] - m);
      __syncthreads();
      for (int s = 128; s > 0; s >>= 1) {
        if (tid < s) rm[tid] += rm[tid + s];
        __syncthreads();
      }
      if (tid == 0) {
        float ssum = rm[0];
        float lsel = cloadf(g_logits + (size_t)b * NN + sel);
        float p = expf(lsel - m) / ssum;
        lp += logf(p + 1e-9f);
        __hip_atomic_store(&g_idx[b], sel, __ATOMIC_RELAXED,
                           __HIP_MEMORY_SCOPE_AGENT);
        savail[sel >> 5] &= ~(1u << (sel & 31));
        out_perm[(size_t)b * NN * NN + (size_t)t * NN + sel] = 1.0f;
        if (t == NN - 1) out_lp[b] = lp;
      }
    }
    gbar(4u * t + 3u);
  }
}

// ---------------- host ----------------
extern "C" void kernel_launch(void* const* d_in, const int* in_sizes, int n_in,
                              void* d_out, int out_size, void* d_ws,
                              size_t ws_size, hipStream_t stream) {
  (void)in_sizes; (void)n_in; (void)d_ws; (void)ws_size;
  const float* W_ih0 = (const float*)d_in[1];
  const float* W_hh0 = (const float*)d_in[2];
  const float* b_ih0 = (const float*)d_in[3];
  const float* b_hh0 = (const float*)d_in[4];
  const float* W_ih1 = (const float*)d_in[5];
  const float* W_hh1 = (const float*)d_in[6];
  const float* b_ih1 = (const float*)d_in[7];
  const float* b_hh1 = (const float*)d_in[8];
  const float* W_out = (const float*)d_in[9];
  const float* b_out = (const float*)d_in[10];

  float* out = (float*)d_out;
  float* out_lp = out + (size_t)BB * NN * NN;

  hipMemsetAsync(d_out, 0, (size_t)out_size * sizeof(float), stream);
  init_state_kernel<<<1024, 256, 0, stream>>>();
  ones_row_kernel<<<6, 256, 0, stream>>>(W_ih0, b_ih0);
  transpose_kernel<<<dim3(16, 48), 256, 0, stream>>>(W_ih0);

  short* whh0; hipGetSymbolAddress((void**)&whh0, HIP_SYMBOL(g_Whh0));
  short* whh1; hipGetSymbolAddress((void**)&whh1, HIP_SYMBOL(g_Whh1));
  short* wih1; hipGetSymbolAddress((void**)&wih1, HIP_SYMBOL(g_Wih1));
  short* wout; hipGetSymbolAddress((void**)&wout, HIP_SYMBOL(g_Wout));
  split_kernel<<<384, 256, 0, stream>>>(W_hh0, whh0, G3, 786432);
  split_kernel<<<384, 256, 0, stream>>>(W_hh1, whh1, G3, 786432);
  split_kernel<<<384, 256, 0, stream>>>(W_ih1, wih1, G3, 786432);
  split_kernel<<<128, 256, 0, stream>>>(W_out, wout, NN, 262144);

  persist_kernel<<<NBLK, 256, 0, stream>>>(b_ih0, b_hh0, b_ih1, b_hh1, b_out,
                                           out, out_lp);
}

// Round 5
// 40463.092 us; speedup vs baseline: 2.1518x; 1.0839x over previous
//
#include <hip/hip_runtime.h>
#include <cstdint>
#include <cstddef>

// B=256 batch, n=512 classes/steps, H=512 hidden, 3H=1536.
#define BB 256
#define NN 512
#define HH 512
#define G3 1536
#define NBLK 256

typedef short bf16x8 __attribute__((ext_vector_type(8)));
typedef float f32x4 __attribute__((ext_vector_type(4)));

// ---------------- static device state ----------------
// Weight planes (hi then lo), MFMA fragment order. 1536-row weights use
// GATE-INTERLEAVED tiles: tile(c) = ((c&511)>>4)*3 + (c>>9)  (c = W row), so
// tile hb*3+g holds rows {g*512 + hb*16 + i}. W_out: tile = c>>4.
// Fragment offset: (tile*16 + S)*512 + qu*128 + ci*8 + j   (S=k>>5 etc).
__device__ __align__(16) short g_Whh0[2 * 786432];
__device__ __align__(16) short g_Whh1[2 * 786432];
__device__ __align__(16) short g_Wih1[2 * 786432];
__device__ __align__(16) short g_Wout[2 * 262144];
// fp32 h state, double buffered, row-major [b][h].
__device__ __align__(16) float g_h0[2][BB * HH];
__device__ __align__(16) float g_h1[2][BB * HH];
__device__ __align__(16) float g_logits[BB * NN];
__device__ __align__(16) float g_WihT[NN * G3];  // W_ih0^T (constant, cached)
__device__ __align__(16) float g_ones[G3];       // gi0 at t=0 (incl b_ih0)
__device__ int g_idx[BB];
__device__ unsigned g_bcnt[16 * 32];  // per-mt-group arrive counters
__device__ unsigned g_bgen[16 * 32];  // per-mt-group generation

// ---------------- coherent (agent-scope) access ----------------
__device__ __forceinline__ unsigned long long cload_u64(const void* p) {
  return __hip_atomic_load((const unsigned long long*)p, __ATOMIC_RELAXED,
                           __HIP_MEMORY_SCOPE_AGENT);
}
__device__ __forceinline__ float cloadf(const float* p) {
  return __hip_atomic_load(p, __ATOMIC_RELAXED, __HIP_MEMORY_SCOPE_AGENT);
}
__device__ __forceinline__ void cstoref(float* p, float v) {
  __hip_atomic_store(p, v, __ATOMIC_RELAXED, __HIP_MEMORY_SCOPE_AGENT);
}

// ---------------- bf16 hi/lo split helpers ----------------
__device__ __forceinline__ unsigned short bf16_rne(float f) {
  uint32_t u = __float_as_uint(f);
  uint32_t r = u + 0x7FFFu + ((u >> 16) & 1u);
  return (unsigned short)(r >> 16);
}
__device__ __forceinline__ float bf16_to_f(unsigned short h) {
  return __uint_as_float(((uint32_t)h) << 16);
}

// ---------------- threefry2x32 (JAX-exact, 20 rounds) ----------------
__device__ __forceinline__ uint32_t rotl32(uint32_t v, int r) {
  return (v << r) | (v >> (32 - r));
}
__device__ __forceinline__ void threefry2x32(uint32_t k0, uint32_t k1,
                                             uint32_t x0, uint32_t x1,
                                             uint32_t& o0, uint32_t& o1) {
  uint32_t k2 = k0 ^ k1 ^ 0x1BD11BDAu;
  x0 += k0; x1 += k1;
  x0 += x1; x1 = rotl32(x1, 13); x1 ^= x0;
  x0 += x1; x1 = rotl32(x1, 15); x1 ^= x0;
  x0 += x1; x1 = rotl32(x1, 26); x1 ^= x0;
  x0 += x1; x1 = rotl32(x1, 6);  x1 ^= x0;
  x0 += k1; x1 += k2 + 1u;
  x0 += x1; x1 = rotl32(x1, 17); x1 ^= x0;
  x0 += x1; x1 = rotl32(x1, 29); x1 ^= x0;
  x0 += x1; x1 = rotl32(x1, 16); x1 ^= x0;
  x0 += x1; x1 = rotl32(x1, 24); x1 ^= x0;
  x0 += k2; x1 += k0 + 2u;
  x0 += x1; x1 = rotl32(x1, 13); x1 ^= x0;
  x0 += x1; x1 = rotl32(x1, 15); x1 ^= x0;
  x0 += x1; x1 = rotl32(x1, 26); x1 ^= x0;
  x0 += x1; x1 = rotl32(x1, 6);  x1 ^= x0;
  x0 += k0; x1 += k1 + 3u;
  x0 += x1; x1 = rotl32(x1, 17); x1 ^= x0;
  x0 += x1; x1 = rotl32(x1, 29); x1 ^= x0;
  x0 += x1; x1 = rotl32(x1, 16); x1 ^= x0;
  x0 += x1; x1 = rotl32(x1, 24); x1 ^= x0;
  x0 += k1; x1 += k2 + 4u;
  x0 += x1; x1 = rotl32(x1, 13); x1 ^= x0;
  x0 += x1; x1 = rotl32(x1, 15); x1 ^= x0;
  x0 += x1; x1 = rotl32(x1, 26); x1 ^= x0;
  x0 += x1; x1 = rotl32(x1, 6);  x1 ^= x0;
  x0 += k2; x1 += k0 + 5u;
  o0 = x0; o1 = x1;
}

// ---------------- prelude kernels ----------------
__global__ __launch_bounds__(256) void init_state_kernel() {
  int i = blockIdx.x * 256 + threadIdx.x;  // 1024*256 = 262144 threads
  if (i < 2 * BB * HH) {
    ((float*)g_h0)[i] = 0.0f;
    ((float*)g_h1)[i] = 0.0f;
  }
  if (i < 16 * 32) { g_bcnt[i] = 0u; g_bgen[i] = 0u; }
  if (i < BB) g_idx[i] = 0;
}

__global__ __launch_bounds__(256) void ones_row_kernel(
    const float* __restrict__ W_ih0, const float* __restrict__ b_ih0) {
  int j = blockIdx.x * 256 + threadIdx.x;
  if (j < G3) {
    const float* row = W_ih0 + (size_t)j * NN;
    float s = 0.0f;
    for (int k = 0; k < NN; ++k) s += row[k];
    g_ones[j] = s + b_ih0[j];
  }
}

__global__ __launch_bounds__(256) void transpose_kernel(
    const float* __restrict__ in) {
  __shared__ float tile[32][33];
  int bx = blockIdx.x;  // over NN, 16
  int by = blockIdx.y;  // over G3, 48
  int tx = threadIdx.x & 31;
  int ty = threadIdx.x >> 5;
  for (int i = 0; i < 32; i += 8)
    tile[ty + i][tx] = in[(size_t)(by * 32 + ty + i) * NN + bx * 32 + tx];
  __syncthreads();
  for (int i = 0; i < 32; i += 8)
    g_WihT[(size_t)(bx * 32 + ty + i) * G3 + by * 32 + tx] = tile[tx][ty + i];
}

__global__ __launch_bounds__(256) void split_kernel(
    const float* __restrict__ W, short* __restrict__ dst, int rows,
    int plane) {
  int i = blockIdx.x * 256 + threadIdx.x;  // rows*64 threads
  if (i >= rows * 64) return;
  int c = i >> 6;
  int jb = i & 63;
  int ci = c & 15;
  int tile = (rows == G3) ? (((c & 511) >> 4) * 3 + (c >> 9)) : (c >> 4);
  int S = jb >> 2, qu = jb & 3;
  int off = (tile * 16 + S) * 512 + qu * 128 + ci * 8;
  const float* src = W + (size_t)c * 512 + jb * 8;
  float v[8];
  *(float4*)v = *(const float4*)src;
  *(float4*)(v + 4) = *(const float4*)(src + 4);
  short hb[8], lb[8];
#pragma unroll
  for (int e = 0; e < 8; ++e) {
    unsigned short h = bf16_rne(v[e]);
    hb[e] = (short)h;
    lb[e] = (short)bf16_rne(v[e] - bf16_to_f(h));
  }
  *(bf16x8*)(dst + off) = *(const bf16x8*)hb;
  *(bf16x8*)(dst + plane + off) = *(const bf16x8*)lb;
}

// ---------------- 16-block group barrier (mt-local) ----------------
__device__ __forceinline__ void gbar(int mt, unsigned bi) {
  __syncthreads();
  if (threadIdx.x == 0) {
    unsigned old = __hip_atomic_fetch_add(&g_bcnt[mt * 32], 1u,
                                          __ATOMIC_RELEASE,
                                          __HIP_MEMORY_SCOPE_AGENT);
    if (old == bi * 16u + 15u)
      __hip_atomic_fetch_add(&g_bgen[mt * 32], 1u, __ATOMIC_RELEASE,
                             __HIP_MEMORY_SCOPE_AGENT);
    while (__hip_atomic_load(&g_bgen[mt * 32], __ATOMIC_RELAXED,
                             __HIP_MEMORY_SCOPE_AGENT) <= bi)
      __builtin_amdgcn_s_sleep(1);
  }
  __syncthreads();
}

// ---------------- bulk A staging: 16 rows x 512 K -> hi/lo LDS ----------
// Fragment LDS layout: off(m,k) = (k>>5)*512 + ((k>>3)&3)*128 + m*8 + (k&7)
__device__ __forceinline__ void stage_h(short A[2][8192],
                                        const float* __restrict__ src,
                                        int tid) {
#pragma unroll
  for (int it = 0; it < 4; ++it) {
    int i = tid + it * 256;       // chunk 0..1023
    int m = i >> 6, c8 = i & 63;  // row, 8-elem k-chunk
    const float* s = src + m * 512 + c8 * 8;
    float v[8];
#pragma unroll
    for (int e = 0; e < 4; ++e) {
      union { unsigned long long q; float f[2]; } u;
      u.q = cload_u64(s + e * 2);
      v[e * 2] = u.f[0];
      v[e * 2 + 1] = u.f[1];
    }
    short hb[8], lb[8];
#pragma unroll
    for (int e = 0; e < 8; ++e) {
      unsigned short h = bf16_rne(v[e]);
      hb[e] = (short)h;
      lb[e] = (short)bf16_rne(v[e] - bf16_to_f(h));
    }
    int off = (c8 >> 2) * 512 + (c8 & 3) * 128 + m * 8;
    *(bf16x8*)&A[0][off] = *(const bf16x8*)hb;
    *(bf16x8*)&A[1][off] = *(const bf16x8*)lb;
  }
}

// ---------------- fragment GEMM: A from LDS, W plain-cached ----------------
__device__ __forceinline__ f32x4 mfma16(bf16x8 a, bf16x8 b, f32x4 c) {
  return __builtin_amdgcn_mfma_f32_16x16x32_bf16(a, b, c, 0, 0, 0);
}

template <int NT>
__device__ __forceinline__ void gemm_lds(const short A[2][8192],
                                         const short* __restrict__ Wp,
                                         int wplane, int t0, int lnoff,
                                         f32x4* acc) {
#pragma unroll
  for (int S = 0; S < 16; ++S) {
    bf16x8 ah = *(const bf16x8*)&A[0][S * 512 + lnoff];
    bf16x8 al = *(const bf16x8*)&A[1][S * 512 + lnoff];
#pragma unroll
    for (int j = 0; j < NT; ++j) {
      const short* wb = Wp + ((t0 + j) * 16 + S) * 512 + lnoff;
      bf16x8 bh = *(const bf16x8*)wb;
      bf16x8 bl = *(const bf16x8*)(wb + wplane);
      acc[j] = mfma16(ah, bh, acc[j]);
      acc[j] = mfma16(ah, bl, acc[j]);
      acc[j] = mfma16(al, bh, acc[j]);
    }
  }
}

__device__ __forceinline__ float sigf(float x) {
  return 1.0f / (1.0f + expf(-x));
}

// ---------------- persistent kernel ----------------
// block bid = mt*16 + ng: mt = 16 batch rows (mt*16..+15), ng = 2 h-blocks
// (hb = ng*2, ng*2+1). All cross-block traffic is mt-local (16 blocks).
// Waves: phase A: w0,w1 = gh0+cell0 (hl=w), w2,w3 = gh1 (acc kept in regs);
// phase B: w2,w3 = gi1+cell1; phase C: w0,w1 = logits; phase D: sampler.
__global__ __launch_bounds__(256, 2) void persist_kernel(
    const float* __restrict__ b_ih0, const float* __restrict__ b_hh0,
    const float* __restrict__ b_ih1, const float* __restrict__ b_hh1,
    const float* __restrict__ b_out, float* __restrict__ out_perm,
    float* __restrict__ out_lp) {
  const int bid = blockIdx.x;
  const int mt = bid >> 4, ng = bid & 15;
  const int hb0 = ng * 2;
  const int tid = threadIdx.x;
  const int w = tid >> 6, ln = tid & 63;
  const int ci = ln & 15, qu = ln >> 4;
  const int lnoff = ln * 8;

  __shared__ short As0[2][8192];  // 32 KB
  __shared__ short As1[2][8192];  // 32 KB
  __shared__ float rv[256];
  __shared__ int ri[256];
  __shared__ float rm[256];
  __shared__ unsigned savail[16];
  __shared__ char pad_[20480];  // force LDS>80KB => exactly 1 block/CU

  if ((uintptr_t)out_perm == 1) ((volatile char*)pad_)[tid] = 1;  // keep pad_

  float h0prev[4] = {0.f, 0.f, 0.f, 0.f};
  float h1prev[4] = {0.f, 0.f, 0.f, 0.f};
  float lp = 0.f;

  if (tid < 16) savail[tid] = 0xFFFFFFFFu;
  __syncthreads();

  for (int t = 0; t < NN; ++t) {
    const int p = t & 1;

    // ================= phase A =================
    stage_h(As0, &g_h0[p][mt * 16 * 512], tid);
    stage_h(As1, &g_h1[p][mt * 16 * 512], tid);

    // prefetch one-hot gather rows for cell0 (constant table, plain loads)
    float pir[4], piz[4], pin[4];
    if (w < 2) {
      const int h = (hb0 + w) * 16 + ci;
      if (t == 0) {
#pragma unroll
        for (int r = 0; r < 4; ++r) {
          pir[r] = g_ones[h];
          piz[r] = g_ones[HH + h];
          pin[r] = g_ones[2 * HH + h];
        }
      } else {
        const float bi0 = b_ih0[h], bi1 = b_ih0[HH + h],
                    bi2 = b_ih0[2 * HH + h];
#pragma unroll
        for (int r = 0; r < 4; ++r) {
          const int b = mt * 16 + qu * 4 + r;
          int iv = __hip_atomic_load(&g_idx[b], __ATOMIC_RELAXED,
                                     __HIP_MEMORY_SCOPE_AGENT);
          const float* wr_ = g_WihT + (size_t)iv * G3;
          pir[r] = wr_[h] + bi0;
          piz[r] = wr_[HH + h] + bi1;
          pin[r] = wr_[2 * HH + h] + bi2;
        }
      }
    }
    __syncthreads();

    f32x4 gh1acc[3];
    gh1acc[0] = (f32x4){0.f, 0.f, 0.f, 0.f};
    gh1acc[1] = gh1acc[0];
    gh1acc[2] = gh1acc[0];

    if (w < 2) {
      f32x4 acc[3];
      acc[0] = (f32x4){0.f, 0.f, 0.f, 0.f};
      acc[1] = acc[0];
      acc[2] = acc[0];
      gemm_lds<3>(As0, g_Whh0, 786432, (hb0 + w) * 3, lnoff, acc);
      const int h = (hb0 + w) * 16 + ci;
      const float br = b_hh0[h], bz = b_hh0[HH + h], bn = b_hh0[2 * HH + h];
#pragma unroll
      for (int r = 0; r < 4; ++r) {
        const int b = mt * 16 + qu * 4 + r;
        float rr = sigf(pir[r] + acc[0][r] + br);
        float zz = sigf(piz[r] + acc[1][r] + bz);
        float ngv = tanhf(pin[r] + rr * (acc[2][r] + bn));
        float hn = (1.f - zz) * ngv + zz * h0prev[r];
        h0prev[r] = hn;
        cstoref(&g_h0[p ^ 1][b * 512 + h], hn);
      }
    } else {
      gemm_lds<3>(As1, g_Whh1, 786432, (hb0 + (w - 2)) * 3, lnoff, gh1acc);
    }
    gbar(mt, 4u * t + 0u);

    // ================= phase B =================
    stage_h(As0, &g_h0[p ^ 1][mt * 16 * 512], tid);
    __syncthreads();
    if (w >= 2) {
      f32x4 gi[3];
      gi[0] = (f32x4){0.f, 0.f, 0.f, 0.f};
      gi[1] = gi[0];
      gi[2] = gi[0];
      gemm_lds<3>(As0, g_Wih1, 786432, (hb0 + (w - 2)) * 3, lnoff, gi);
      const int h = (hb0 + (w - 2)) * 16 + ci;
      const float bi0 = b_ih1[h], bi1 = b_ih1[HH + h], bi2 = b_ih1[2 * HH + h];
      const float c0 = b_hh1[h], c1 = b_hh1[HH + h], c2 = b_hh1[2 * HH + h];
#pragma unroll
      for (int r = 0; r < 4; ++r) {
        const int b = mt * 16 + qu * 4 + r;
        float rr = sigf(gi[0][r] + bi0 + gh1acc[0][r] + c0);
        float zz = sigf(gi[1][r] + bi1 + gh1acc[1][r] + c1);
        float ngv = tanhf(gi[2][r] + bi2 + rr * (gh1acc[2][r] + c2));
        float hn = (1.f - zz) * ngv + zz * h1prev[r];
        h1prev[r] = hn;
        cstoref(&g_h1[p ^ 1][b * 512 + h], hn);
      }
    }
    gbar(mt, 4u * t + 1u);

    // ================= phase C =================
    stage_h(As1, &g_h1[p ^ 1][mt * 16 * 512], tid);
    __syncthreads();
    if (w < 2) {
      f32x4 a1[1];
      a1[0] = (f32x4){0.f, 0.f, 0.f, 0.f};
      gemm_lds<1>(As1, g_Wout, 262144, ng * 2 + w, lnoff, a1);
      const int n = (ng * 2 + w) * 16 + ci;
      const float bo = b_out[n];
#pragma unroll
      for (int r = 0; r < 4; ++r) {
        const int b = mt * 16 + qu * 4 + r;
        cstoref(&g_logits[b * 512 + n], a1[0][r] + bo);
      }
    }
    gbar(mt, 4u * t + 2u);

    // ================= phase D: sampler, row b = bid =================
    {
      const int b = bid;
      uint32_t tp = (uint32_t)(t & 255);
      uint32_t a0, a1k, c0, c1;
      threefry2x32(0u, 42u, 2u * tp, 2u * tp + 512u, a0, a1k);
      threefry2x32(0u, 42u, 2u * tp + 1u, 2u * tp + 1u + 512u, c0, c1);
      uint32_t sk0 = (t < 256) ? a0 : a1k;
      uint32_t sk1 = (t < 256) ? c0 : c1;

      float bestv = -1.0f / 0.0f;
      int besti = 0;
      float mymax = -1.0f / 0.0f;
      float ml[2];
#pragma unroll
      for (int j = 0; j < 2; ++j) {
        int c = tid + j * 256;
        uint32_t cnt = (uint32_t)(b & 127) * 512u + (uint32_t)c;
        uint32_t r0, r1;
        threefry2x32(sk0, sk1, cnt, cnt + 65536u, r0, r1);
        uint32_t bits = (b < 128) ? r0 : r1;
        float u = __uint_as_float((bits >> 9) | 0x3f800000u) - 1.0f;
        if (u == 0.0f) u = 1.17549435e-38f;
        float g = -logf(-logf(u));
        float l = cloadf(&g_logits[b * 512 + c]);
        bool av = (savail[c >> 5] >> (c & 31)) & 1u;
        float mlv = av ? l : -1.0e9f;
        ml[j] = mlv;
        float v = g + mlv;
        if (v > bestv || (v == bestv && c < besti)) { bestv = v; besti = c; }
        mymax = fmaxf(mymax, mlv);
      }
      rv[tid] = bestv; ri[tid] = besti; rm[tid] = mymax;
      __syncthreads();
      for (int s = 128; s > 0; s >>= 1) {
        if (tid < s) {
          float v2 = rv[tid + s]; int i2 = ri[tid + s];
          if (v2 > rv[tid] || (v2 == rv[tid] && i2 < ri[tid])) {
            rv[tid] = v2; ri[tid] = i2;
          }
          rm[tid] = fmaxf(rm[tid], rm[tid + s]);
        }
        __syncthreads();
      }
      float m = rm[0];
      int sel = ri[0];
      __syncthreads();
      rm[tid] = expf(ml[0] - m) + expf(ml[1] - m);
      __syncthreads();
      for (int s = 128; s > 0; s >>= 1) {
        if (tid < s) rm[tid] += rm[tid + s];
        __syncthreads();
      }
      if (tid == 0) {
        float ssum = rm[0];
        float lsel = cloadf(&g_logits[b * 512 + sel]);
        float pz = expf(lsel - m) / ssum;
        lp += logf(pz + 1e-9f);
        __hip_atomic_store(&g_idx[b], sel, __ATOMIC_RELAXED,
                           __HIP_MEMORY_SCOPE_AGENT);
        savail[sel >> 5] &= ~(1u << (sel & 31));
        out_perm[(size_t)b * NN * NN + (size_t)t * NN + sel] = 1.0f;
        if (t == NN - 1) out_lp[b] = lp;
      }
    }
    gbar(mt, 4u * t + 3u);
  }
}

// ---------------- host ----------------
extern "C" void kernel_launch(void* const* d_in, const int* in_sizes, int n_in,
                              void* d_out, int out_size, void* d_ws,
                              size_t ws_size, hipStream_t stream) {
  (void)in_sizes; (void)n_in; (void)d_ws; (void)ws_size;
  const float* W_ih0 = (const float*)d_in[1];
  const float* W_hh0 = (const float*)d_in[2];
  const float* b_ih0 = (const float*)d_in[3];
  const float* b_hh0 = (const float*)d_in[4];
  const float* W_ih1 = (const float*)d_in[5];
  const float* W_hh1 = (const float*)d_in[6];
  const float* b_ih1 = (const float*)d_in[7];
  const float* b_hh1 = (const float*)d_in[8];
  const float* W_out = (const float*)d_in[9];
  const float* b_out = (const float*)d_in[10];

  float* out = (float*)d_out;
  float* out_lp = out + (size_t)BB * NN * NN;

  hipMemsetAsync(d_out, 0, (size_t)out_size * sizeof(float), stream);
  init_state_kernel<<<1024, 256, 0, stream>>>();
  ones_row_kernel<<<6, 256, 0, stream>>>(W_ih0, b_ih0);
  transpose_kernel<<<dim3(16, 48), 256, 0, stream>>>(W_ih0);

  short* whh0; hipGetSymbolAddress((void**)&whh0, HIP_SYMBOL(g_Whh0));
  short* whh1; hipGetSymbolAddress((void**)&whh1, HIP_SYMBOL(g_Whh1));
  short* wih1; hipGetSymbolAddress((void**)&wih1, HIP_SYMBOL(g_Wih1));
  short* wout; hipGetSymbolAddress((void**)&wout, HIP_SYMBOL(g_Wout));
  split_kernel<<<384, 256, 0, stream>>>(W_hh0, whh0, G3, 786432);
  split_kernel<<<384, 256, 0, stream>>>(W_hh1, whh1, G3, 786432);
  split_kernel<<<384, 256, 0, stream>>>(W_ih1, wih1, G3, 786432);
  split_kernel<<<128, 256, 0, stream>>>(W_out, wout, NN, 262144);

  persist_kernel<<<NBLK, 256, 0, stream>>>(b_ih0, b_hh0, b_ih1, b_hh1, b_out,
                                           out, out_lp);
}

// Round 6
// 28262.955 us; speedup vs baseline: 3.0807x; 1.4317x over previous
//
#include <hip/hip_runtime.h>
#include <cstdint>
#include <cstddef>

// B=256 batch, n=512 classes/steps, H=512 hidden, 3H=1536.
#define BB 256
#define NN 512
#define HH 512
#define G3 1536

typedef short bf16x8 __attribute__((ext_vector_type(8)));
typedef float f32x4 __attribute__((ext_vector_type(4)));

// ---------------- static device state ----------------
// Weight planes (hi then lo), MFMA fragment order. 1536-row weights use
// GATE-INTERLEAVED tiles: tile(c) = ((c&511)>>4)*3 + (c>>9)  (c = W row):
// tile u*3+g holds rows {g*512 + u*16 + i}. W_out: tile = c>>4.
// Fragment offset: (tile*16 + S)*512 + qu*128 + ci*8 + j   (S=k>>5 etc).
__device__ __align__(16) short g_Whh0[2 * 786432];
__device__ __align__(16) short g_Whh1[2 * 786432];
__device__ __align__(16) short g_Wih1[2 * 786432];
__device__ __align__(16) short g_Wout[2 * 262144];
// h-state bf16 hi/lo planes, double buffered by parity; A-fragment order:
// off(b,h) = (b>>4)*8192 + (h>>5)*512 + ((h>>3)&3)*128 + (b&15)*8 + (h&7)
__device__ __align__(16) short g_h0p[2][2 * 131072];
__device__ __align__(16) short g_h1p[2][2 * 131072];
__device__ __align__(16) float g_h0f[BB * HH];   // exact fp32 hold terms
__device__ __align__(16) float g_h1f[BB * HH];   // (same-thread-role RMW)
__device__ __align__(16) float g_gh1[BB * G3];   // [b][g*512+h], incl b_hh1
__device__ __align__(16) float g_logits[2][BB * NN];  // atomic partial sums
__device__ __align__(16) float g_gum[2][BB * NN];     // per-step gumbels
__device__ __align__(16) float g_WihT[NN * G3];  // W_ih0^T rows for gather
__device__ __align__(16) float g_ones[G3];       // gi0 at t=0 (incl b_ih0)
__device__ float g_lp[BB];
__device__ unsigned g_avail[2][BB * 16];
__device__ int g_idx[BB];

// ---------------- bf16 hi/lo helpers ----------------
__device__ __forceinline__ unsigned short bf16_rne(float f) {
  uint32_t u = __float_as_uint(f);
  uint32_t r = u + 0x7FFFu + ((u >> 16) & 1u);
  return (unsigned short)(r >> 16);
}
__device__ __forceinline__ float bf16_to_f(unsigned short h) {
  return __uint_as_float(((uint32_t)h) << 16);
}
__device__ __forceinline__ float sigf(float x) {
  return 1.0f / (1.0f + expf(-x));
}
__device__ __forceinline__ f32x4 mfma16(bf16x8 a, bf16x8 b, f32x4 c) {
  return __builtin_amdgcn_mfma_f32_16x16x32_bf16(a, b, c, 0, 0, 0);
}

// ---------------- threefry2x32 (JAX-exact, 20 rounds) ----------------
__device__ __forceinline__ uint32_t rotl32(uint32_t v, int r) {
  return (v << r) | (v >> (32 - r));
}
__device__ __forceinline__ void threefry2x32(uint32_t k0, uint32_t k1,
                                             uint32_t x0, uint32_t x1,
                                             uint32_t& o0, uint32_t& o1) {
  uint32_t k2 = k0 ^ k1 ^ 0x1BD11BDAu;
  x0 += k0; x1 += k1;
  x0 += x1; x1 = rotl32(x1, 13); x1 ^= x0;
  x0 += x1; x1 = rotl32(x1, 15); x1 ^= x0;
  x0 += x1; x1 = rotl32(x1, 26); x1 ^= x0;
  x0 += x1; x1 = rotl32(x1, 6);  x1 ^= x0;
  x0 += k1; x1 += k2 + 1u;
  x0 += x1; x1 = rotl32(x1, 17); x1 ^= x0;
  x0 += x1; x1 = rotl32(x1, 29); x1 ^= x0;
  x0 += x1; x1 = rotl32(x1, 16); x1 ^= x0;
  x0 += x1; x1 = rotl32(x1, 24); x1 ^= x0;
  x0 += k2; x1 += k0 + 2u;
  x0 += x1; x1 = rotl32(x1, 13); x1 ^= x0;
  x0 += x1; x1 = rotl32(x1, 15); x1 ^= x0;
  x0 += x1; x1 = rotl32(x1, 26); x1 ^= x0;
  x0 += x1; x1 = rotl32(x1, 6);  x1 ^= x0;
  x0 += k0; x1 += k1 + 3u;
  x0 += x1; x1 = rotl32(x1, 17); x1 ^= x0;
  x0 += x1; x1 = rotl32(x1, 29); x1 ^= x0;
  x0 += x1; x1 = rotl32(x1, 16); x1 ^= x0;
  x0 += x1; x1 = rotl32(x1, 24); x1 ^= x0;
  x0 += k1; x1 += k2 + 4u;
  x0 += x1; x1 = rotl32(x1, 13); x1 ^= x0;
  x0 += x1; x1 = rotl32(x1, 15); x1 ^= x0;
  x0 += x1; x1 = rotl32(x1, 26); x1 ^= x0;
  x0 += x1; x1 = rotl32(x1, 6);  x1 ^= x0;
  x0 += k2; x1 += k0 + 5u;
  o0 = x0; o1 = x1;
}

__device__ __forceinline__ float gumbel_from_bits(uint32_t bits) {
  float u = __uint_as_float((bits >> 9) | 0x3f800000u) - 1.0f;
  if (u == 0.0f) u = 1.17549435e-38f;
  return -logf(-logf(u));
}

// ---------------- prelude kernels ----------------
__global__ __launch_bounds__(256) void init_state_kernel() {
  int i = blockIdx.x * 256 + threadIdx.x;  // 1024 blocks -> 262144 threads
  if (i < BB * HH) { g_h0f[i] = 0.0f; g_h1f[i] = 0.0f; }
  if (i < 262144) {  // both parities+planes: 524288 shorts = 262144 u32
    ((uint32_t*)g_h0p)[i] = 0u;
    ((uint32_t*)g_h1p)[i] = 0u;
  }
  if (i < 2 * BB * 16) ((unsigned*)g_avail)[i] = 0xFFFFFFFFu;
  if (i < BB) { g_lp[i] = 0.0f; g_idx[i] = 0; }
}

__global__ __launch_bounds__(256) void ones_row_kernel(
    const float* __restrict__ W_ih0, const float* __restrict__ b_ih0) {
  int j = blockIdx.x * 256 + threadIdx.x;
  if (j < G3) {
    const float* row = W_ih0 + (size_t)j * NN;
    float s = 0.0f;
    for (int k = 0; k < NN; ++k) s += row[k];
    g_ones[j] = s + b_ih0[j];
  }
}

__global__ __launch_bounds__(256) void transpose_kernel(
    const float* __restrict__ in) {
  __shared__ float tile[32][33];
  int bx = blockIdx.x;  // over NN, 16
  int by = blockIdx.y;  // over G3, 48
  int tx = threadIdx.x & 31;
  int ty = threadIdx.x >> 5;
  for (int i = 0; i < 32; i += 8)
    tile[ty + i][tx] = in[(size_t)(by * 32 + ty + i) * NN + bx * 32 + tx];
  __syncthreads();
  for (int i = 0; i < 32; i += 8)
    g_WihT[(size_t)(bx * 32 + ty + i) * G3 + by * 32 + tx] = tile[tx][ty + i];
}

__global__ __launch_bounds__(256) void split_kernel(
    const float* __restrict__ W, short* __restrict__ dst, int rows,
    int plane) {
  int i = blockIdx.x * 256 + threadIdx.x;  // rows*64 threads
  if (i >= rows * 64) return;
  int c = i >> 6;   // original W row
  int jb = i & 63;  // 8-elem k-chunk
  int ci = c & 15;
  int tile = (rows == G3) ? (((c & 511) >> 4) * 3 + (c >> 9)) : (c >> 4);
  int S = jb >> 2, qu = jb & 3;
  int off = (tile * 16 + S) * 512 + qu * 128 + ci * 8;
  const float* src = W + (size_t)c * 512 + jb * 8;
  float v[8];
  *(float4*)v = *(const float4*)src;
  *(float4*)(v + 4) = *(const float4*)(src + 4);
  short hb[8], lb[8];
#pragma unroll
  for (int e = 0; e < 8; ++e) {
    unsigned short h = bf16_rne(v[e]);
    hb[e] = (short)h;
    lb[e] = (short)bf16_rne(v[e] - bf16_to_f(h));
  }
  *(bf16x8*)(dst + off) = *(const bf16x8*)hb;
  *(bf16x8*)(dst + plane + off) = *(const bf16x8*)lb;
}

// ---------------- K0: replay sampler(t-1) + finalize + zero logits(t) ------
// grid 16 blocks (one per mt), 256 threads: 16 rows x 16 lanes (32 cols each).
__global__ __launch_bounds__(256) void k0_sample(
    int t, const float* __restrict__ b_out, float* __restrict__ out_perm,
    float* __restrict__ out_lp) {
  const int mt = blockIdx.x;
  const int tid = threadIdx.x;
  if (t < NN) {  // zero this step's logits accumulator (parity t&1)
    float* lz = g_logits[t & 1] + mt * 16 * NN;
    for (int i = tid; i < 16 * NN; i += 256) lz[i] = 0.0f;
  }
  if (t == 0) return;
  const int tp = t - 1;
  const int rr = tid >> 4, l16 = tid & 15;
  const int b = mt * 16 + rr;
  const float* lrow = g_logits[tp & 1] + b * NN;
  const float* grow = g_gum[tp & 1] + b * NN;
  unsigned aw = g_avail[tp & 1][b * 16 + l16];

  float best = -1.0f / 0.0f;
  int bi = 0;
  float sum = 0.0f;
  for (int k = 0; k < 32; ++k) {
    int c = l16 * 32 + k;
    float l = lrow[c] + b_out[c];
    bool av = (aw >> k) & 1u;
    float ml = av ? l : -1.0e9f;
    float v = grow[c] + ml;
    if (v > best || (v == best && c < bi)) { best = v; bi = c; }
    sum += av ? expf(l) : 0.0f;  // == sum exp(masked) since exp(-1e9)=0
  }
  __shared__ float sv[256];
  __shared__ int si[256];
  __shared__ float ss[256];
  sv[tid] = best; si[tid] = bi; ss[tid] = sum;
  __syncthreads();
  for (int s = 8; s > 0; s >>= 1) {
    if (l16 < s) {
      float v2 = sv[tid + s]; int i2 = si[tid + s];
      if (v2 > sv[tid] || (v2 == sv[tid] && i2 < si[tid])) {
        sv[tid] = v2; si[tid] = i2;
      }
      ss[tid] += ss[tid + s];
    }
    __syncthreads();
  }
  const int sel = si[rr * 16];
  const float ssum = ss[rr * 16];
  // avail(t) = avail(t-1) clear sel; each lane writes its word
  unsigned nw = aw;
  if ((sel >> 5) == l16) nw &= ~(1u << (sel & 31));
  g_avail[t & 1][b * 16 + l16] = nw;
  if (l16 == 0) {
    float lsel = lrow[sel] + b_out[sel];
    float p = expf(lsel) / ssum;
    float lpn = g_lp[b] + logf(p + 1e-9f);
    g_lp[b] = lpn;
    out_lp[b] = lpn;
    g_idx[b] = sel;
    out_perm[(size_t)b * NN * NN + (size_t)tp * NN + sel] = 1.0f;
  }
}

// ---------------- K1: gh0+cell0 -> h0' (nb<8) || gh1 (nb>=8) ----------------
// grid 256 = 16 mt x 16 nb; wave-unit u covers one 16-wide h-block (3 tiles).
__global__ __launch_bounds__(256) void k1_layer0(
    int t, const float* __restrict__ b_ih0, const float* __restrict__ b_hh0,
    const float* __restrict__ b_hh1) {
  const int bid = blockIdx.x;
  const int mt = bid >> 4, nb = bid & 15;
  const int tid = threadIdx.x;
  const int w = tid >> 6, ln = tid & 63;
  const int ci = ln & 15, qu = ln >> 4;
  const int lnoff = ln * 8;
  const int rb = t & 1, wb = rb ^ 1;

  f32x4 z = (f32x4){0.f, 0.f, 0.f, 0.f};
  f32x4 acc[3] = {z, z, z};

  const int u = (nb & 7) * 4 + w;
  const short* Ap = (nb < 8) ? g_h0p[rb] : g_h1p[rb];
  const short* Wp = (nb < 8) ? g_Whh0 : g_Whh1;

#pragma unroll
  for (int S = 0; S < 16; ++S) {
    const int aoff = mt * 8192 + S * 512 + lnoff;
    bf16x8 ah = *(const bf16x8*)(Ap + aoff);
    bf16x8 al = *(const bf16x8*)(Ap + 131072 + aoff);
#pragma unroll
    for (int g = 0; g < 3; ++g) {
      const short* wp = Wp + ((u * 3 + g) * 16 + S) * 512 + lnoff;
      bf16x8 bh = *(const bf16x8*)wp;
      bf16x8 bl = *(const bf16x8*)(wp + 786432);
      acc[g] = mfma16(ah, bh, acc[g]);
      acc[g] = mfma16(ah, bl, acc[g]);
      acc[g] = mfma16(al, bh, acc[g]);
    }
  }

  const int h = u * 16 + ci;
  if (nb < 8) {
    const float br = b_hh0[h], bz = b_hh0[HH + h], bn = b_hh0[2 * HH + h];
    const float bi0 = b_ih0[h], bi1 = b_ih0[HH + h], bi2 = b_ih0[2 * HH + h];
#pragma unroll
    for (int r = 0; r < 4; ++r) {
      const int b = mt * 16 + qu * 4 + r;
      float ir, iz, in_;
      if (t == 0) {
        ir = g_ones[h]; iz = g_ones[HH + h]; in_ = g_ones[2 * HH + h];
      } else {
        const float* wr_ = g_WihT + (size_t)g_idx[b] * G3;
        ir = wr_[h] + bi0;
        iz = wr_[HH + h] + bi1;
        in_ = wr_[2 * HH + h] + bi2;
      }
      float rr_ = sigf(ir + acc[0][r] + br);
      float zz = sigf(iz + acc[1][r] + bz);
      float ng = tanhf(in_ + rr_ * (acc[2][r] + bn));
      const int o = b * HH + h;
      float hn = (1.f - zz) * ng + zz * g_h0f[o];
      g_h0f[o] = hn;
      const int off = (b >> 4) * 8192 + (h >> 5) * 512 + ((h >> 3) & 3) * 128 +
                      (b & 15) * 8 + (h & 7);
      unsigned short hi = bf16_rne(hn);
      g_h0p[wb][off] = (short)hi;
      g_h0p[wb][131072 + off] = (short)bf16_rne(hn - bf16_to_f(hi));
    }
  } else {
    const float c0 = b_hh1[h], c1 = b_hh1[HH + h], c2 = b_hh1[2 * HH + h];
#pragma unroll
    for (int r = 0; r < 4; ++r) {
      const int b = mt * 16 + qu * 4 + r;
      float* base = g_gh1 + (size_t)b * G3;
      base[h] = acc[0][r] + c0;
      base[512 + h] = acc[1][r] + c1;
      base[1024 + h] = acc[2][r] + c2;
    }
  }
}

// ---------------- K2: gi1+cell1 -> h1' + partial logits + gumbel(t) --------
// grid 128 = 16 mt x 8 nb.
__global__ __launch_bounds__(256) void k2_layer1(
    int t, const float* __restrict__ b_ih1) {
  const int bid = blockIdx.x;
  const int mt = bid >> 3, nb = bid & 7;
  const int tid = threadIdx.x;
  const int w = tid >> 6, ln = tid & 63;
  const int ci = ln & 15, qu = ln >> 4;
  const int lnoff = ln * 8;
  const int wb = (t & 1) ^ 1;

  f32x4 z = (f32x4){0.f, 0.f, 0.f, 0.f};
  f32x4 acc[3] = {z, z, z};
  const int u = nb * 4 + w;

#pragma unroll
  for (int S = 0; S < 16; ++S) {
    const int aoff = mt * 8192 + S * 512 + lnoff;
    bf16x8 ah = *(const bf16x8*)(g_h0p[wb] + aoff);
    bf16x8 al = *(const bf16x8*)(g_h0p[wb] + 131072 + aoff);
#pragma unroll
    for (int g = 0; g < 3; ++g) {
      const short* wp = g_Wih1 + ((u * 3 + g) * 16 + S) * 512 + lnoff;
      bf16x8 bh = *(const bf16x8*)wp;
      bf16x8 bl = *(const bf16x8*)(wp + 786432);
      acc[g] = mfma16(ah, bh, acc[g]);
      acc[g] = mfma16(ah, bl, acc[g]);
      acc[g] = mfma16(al, bh, acc[g]);
    }
  }

  const int h = u * 16 + ci;
  const float bi0 = b_ih1[h], bi1 = b_ih1[HH + h], bi2 = b_ih1[2 * HH + h];
  float hn[4];
#pragma unroll
  for (int r = 0; r < 4; ++r) {
    const int b = mt * 16 + qu * 4 + r;
    const float* base = g_gh1 + (size_t)b * G3;
    float rr_ = sigf(acc[0][r] + bi0 + base[h]);
    float zz = sigf(acc[1][r] + bi1 + base[512 + h]);
    float ng = tanhf(acc[2][r] + bi2 + rr_ * base[1024 + h]);
    const int o = b * HH + h;
    float v = (1.f - zz) * ng + zz * g_h1f[o];
    g_h1f[o] = v;
    hn[r] = v;
    const int off = (b >> 4) * 8192 + (h >> 5) * 512 + ((h >> 3) & 3) * 128 +
                    (b & 15) * 8 + (h & 7);
    unsigned short hi = bf16_rne(v);
    g_h1p[wb][off] = (short)hi;
    g_h1p[wb][131072 + off] = (short)bf16_rne(v - bf16_to_f(hi));
  }

  // transpose h1' (C-layout) -> A-fragment LDS for the partial-logits MFMA
  __shared__ short Lh[1024], Ll[1024];
  const int kk = w * 16 + ci;  // block-local k (h col) 0..63
#pragma unroll
  for (int r = 0; r < 4; ++r) {
    const int m = qu * 4 + r;
    const int off = (kk >> 5) * 512 + ((kk >> 3) & 3) * 128 + m * 8 + (kk & 7);
    unsigned short hi = bf16_rne(hn[r]);
    Lh[off] = (short)hi;
    Ll[off] = (short)bf16_rne(hn[r] - bf16_to_f(hi));
  }
  __syncthreads();

  f32x4 acc2[8] = {z, z, z, z, z, z, z, z};
#pragma unroll
  for (int S2 = 0; S2 < 2; ++S2) {
    bf16x8 ah = *(const bf16x8*)&Lh[S2 * 512 + lnoff];
    bf16x8 al = *(const bf16x8*)&Ll[S2 * 512 + lnoff];
#pragma unroll
    for (int j = 0; j < 8; ++j) {
      const int nt = w * 8 + j;
      const short* wp = g_Wout + (nt * 16 + nb * 2 + S2) * 512 + lnoff;
      bf16x8 bh = *(const bf16x8*)wp;
      bf16x8 bl = *(const bf16x8*)(wp + 262144);
      acc2[j] = mfma16(ah, bh, acc2[j]);
      acc2[j] = mfma16(ah, bl, acc2[j]);
      acc2[j] = mfma16(al, bh, acc2[j]);
    }
  }
  float* Ldst = g_logits[t & 1];
#pragma unroll
  for (int j = 0; j < 8; ++j) {
    const int n = (w * 8 + j) * 16 + ci;
#pragma unroll
    for (int r = 0; r < 4; ++r) {
      const int b = mt * 16 + qu * 4 + r;
      atomicAdd(&Ldst[b * NN + n], acc2[j][r]);
    }
  }

  // gumbel(t): mt<8 blocks generate rows b and b+128 (threefry counter pair)
  if (mt < 8) {
    uint32_t tp_ = (uint32_t)(t & 255);
    uint32_t a0, a1, c0, c1;
    threefry2x32(0u, 42u, 2u * tp_, 2u * tp_ + 512u, a0, a1);
    threefry2x32(0u, 42u, 2u * tp_ + 1u, 2u * tp_ + 1u + 512u, c0, c1);
    uint32_t sk0 = (t < 256) ? a0 : a1;
    uint32_t sk1 = (t < 256) ? c0 : c1;
    float* G = g_gum[t & 1];
    for (int e = tid; e < 1024; e += 256) {
      const int r16 = e >> 6;
      const int c = nb * 64 + (e & 63);
      const int b = mt * 16 + r16;  // < 128
      uint32_t cnt = (uint32_t)b * 512u + (uint32_t)c;
      uint32_t r0, r1;
      threefry2x32(sk0, sk1, cnt, cnt + 65536u, r0, r1);
      G[b * NN + c] = gumbel_from_bits(r0);
      G[(b + 128) * NN + c] = gumbel_from_bits(r1);
    }
  }
}

// ---------------- host ----------------
extern "C" void kernel_launch(void* const* d_in, const int* in_sizes, int n_in,
                              void* d_out, int out_size, void* d_ws,
                              size_t ws_size, hipStream_t stream) {
  (void)in_sizes; (void)n_in; (void)d_ws; (void)ws_size;
  const float* W_ih0 = (const float*)d_in[1];
  const float* W_hh0 = (const float*)d_in[2];
  const float* b_ih0 = (const float*)d_in[3];
  const float* b_hh0 = (const float*)d_in[4];
  const float* W_ih1 = (const float*)d_in[5];
  const float* W_hh1 = (const float*)d_in[6];
  const float* b_ih1 = (const float*)d_in[7];
  const float* b_hh1 = (const float*)d_in[8];
  const float* W_out = (const float*)d_in[9];
  const float* b_out = (const float*)d_in[10];

  float* out = (float*)d_out;
  float* out_lp = out + (size_t)BB * NN * NN;

  hipMemsetAsync(d_out, 0, (size_t)out_size * sizeof(float), stream);
  init_state_kernel<<<1024, 256, 0, stream>>>();
  ones_row_kernel<<<6, 256, 0, stream>>>(W_ih0, b_ih0);
  transpose_kernel<<<dim3(16, 48), 256, 0, stream>>>(W_ih0);

  short* whh0; hipGetSymbolAddress((void**)&whh0, HIP_SYMBOL(g_Whh0));
  short* whh1; hipGetSymbolAddress((void**)&whh1, HIP_SYMBOL(g_Whh1));
  short* wih1; hipGetSymbolAddress((void**)&wih1, HIP_SYMBOL(g_Wih1));
  short* wout; hipGetSymbolAddress((void**)&wout, HIP_SYMBOL(g_Wout));
  split_kernel<<<384, 256, 0, stream>>>(W_hh0, whh0, G3, 786432);
  split_kernel<<<384, 256, 0, stream>>>(W_hh1, whh1, G3, 786432);
  split_kernel<<<384, 256, 0, stream>>>(W_ih1, wih1, G3, 786432);
  split_kernel<<<128, 256, 0, stream>>>(W_out, wout, NN, 262144);

  for (int t = 0; t < NN; ++t) {
    k0_sample<<<16, 256, 0, stream>>>(t, b_out, out, out_lp);
    k1_layer0<<<256, 256, 0, stream>>>(t, b_ih0, b_hh0, b_hh1);
    k2_layer1<<<128, 256, 0, stream>>>(t, b_ih1);
  }
  // tail: replay and finalize step 511
  k0_sample<<<16, 256, 0, stream>>>(NN, b_out, out, out_lp);
}